// Round 1
// baseline (365.021 us; speedup 1.0000x reference)
//
#include <hip/hip_runtime.h>
#include <math.h>

#define B_    8
#define HH_   64
#define WW_   64
#define C_    128
#define D_    128
#define L_    4096
#define NPOS_ 32768
#define N_    8
#define R_    8
#define NC_   128   // number of scan chunks per batch
#define S_    32    // chunk length (NC_*S_ == L_)
#define NB_   4194304  // one big buffer: NPOS_*128 floats

__device__ __forceinline__ float siluf(float x) { return x / (1.f + __expf(-x)); }
__device__ __forceinline__ float softplusf(float x) {
    if (x > 20.f) return x;
    return log1pf(__expf(x));
}

// ---------------- K1: grouped 1x1 (w1) -> t1 ; silu(grouped 1x1 (w2)) -> x2s ----------------
__global__ __launch_bounds__(128) void k1_g1x1(const float* __restrict__ x,
                                               const float* __restrict__ w1,
                                               const float* __restrict__ w2,
                                               float* __restrict__ t1,
                                               float* __restrict__ x2s) {
    __shared__ float w1T[32 * 128];
    __shared__ float w2T[32 * 128];
    __shared__ float xs[8][128];
    int d = threadIdx.x;
    int g = d >> 5, o = d & 31;
    #pragma unroll
    for (int i = 0; i < 32; ++i) {
        w1T[i * 128 + d] = w1[g * 1024 + o * 32 + i];
        w2T[i * 128 + d] = w2[g * 1024 + o * 32 + i];
    }
    __syncthreads();
    int pos0 = blockIdx.x * 64;
    for (int it = 0; it < 8; ++it) {
        int p0 = pos0 + it * 8;
        #pragma unroll
        for (int q = 0; q < 8; ++q) xs[q][d] = x[(p0 + q) * 128 + d];
        __syncthreads();
        #pragma unroll
        for (int q = 0; q < 8; ++q) {
            float a1 = 0.f, a2 = 0.f;
            const float* xr = &xs[q][g * 32];
            #pragma unroll
            for (int i = 0; i < 32; ++i) {
                float xv = xr[i];
                a1 += xv * w1T[i * 128 + d];
                a2 += xv * w2T[i * 128 + d];
            }
            t1[(p0 + q) * 128 + d]  = a1;
            x2s[(p0 + q) * 128 + d] = siluf(a2);
        }
        __syncthreads();
    }
}

// ---------------- K2: depthwise 3x3 SAME + silu ----------------
__global__ __launch_bounds__(128) void k2_dwconv(const float* __restrict__ t1,
                                                 const float* __restrict__ dw,
                                                 float* __restrict__ x1c) {
    int d = threadIdx.x;
    float dwr[9];
    #pragma unroll
    for (int k = 0; k < 9; ++k) dwr[k] = dw[k * 128 + d];
    int bid = blockIdx.x;          // 8*64*4 = 2048 blocks
    int wq = bid & 3;
    int h  = (bid >> 2) & 63;
    int b  = bid >> 8;
    int w0 = wq * 16;
    for (int wi = 0; wi < 16; ++wi) {
        int w = w0 + wi;
        float acc = 0.f;
        #pragma unroll
        for (int kh = -1; kh <= 1; ++kh) {
            int hh = h + kh;
            if (hh < 0 || hh > 63) continue;
            #pragma unroll
            for (int kw = -1; kw <= 1; ++kw) {
                int ww = w + kw;
                if (ww < 0 || ww > 63) continue;
                acc += t1[((b * 64 + hh) * 64 + ww) * 128 + d] * dwr[(kh + 1) * 3 + (kw + 1)];
            }
        }
        x1c[((b * 64 + h) * 64 + w) * 128 + d] = siluf(acc);
    }
}

// ---------------- K3: in_proj GEMM: xz[pos,e] = sum_d x1c[pos,d]*W[e,d] ----------------
// block: 256 thr, 64 positions x 256 outputs; thread: 16 pos x 4 outputs
__global__ __launch_bounds__(256) void k3_inproj(const float* __restrict__ x1c,
                                                 const float* __restrict__ inW,
                                                 float* __restrict__ uraw,
                                                 float* __restrict__ z) {
    __shared__ float xs[64 * 32];    // [p][dk]
    __shared__ float Wt[32 * 256];   // [dk][e]
    int t  = threadIdx.x;
    int te = t & 63, tp = t >> 6;
    float acc[16][4];
    #pragma unroll
    for (int i = 0; i < 16; ++i)
        #pragma unroll
        for (int j = 0; j < 4; ++j) acc[i][j] = 0.f;
    int pos0 = blockIdx.x * 64;
    for (int kb = 0; kb < 4; ++kb) {
        #pragma unroll
        for (int q = 0; q < 2; ++q) {
            int fi = t * 2 + q;            // 0..511 float4s
            int p = fi >> 3, dk4 = fi & 7;
            float4 v = *(const float4*)&x1c[(pos0 + p) * 128 + kb * 32 + dk4 * 4];
            *(float4*)&xs[p * 32 + dk4 * 4] = v;
        }
        #pragma unroll
        for (int dk4 = 0; dk4 < 8; ++dk4) {
            float4 v = *(const float4*)&inW[t * 128 + kb * 32 + dk4 * 4];
            Wt[(dk4 * 4 + 0) * 256 + t] = v.x;
            Wt[(dk4 * 4 + 1) * 256 + t] = v.y;
            Wt[(dk4 * 4 + 2) * 256 + t] = v.z;
            Wt[(dk4 * 4 + 3) * 256 + t] = v.w;
        }
        __syncthreads();
        #pragma unroll 4
        for (int dk = 0; dk < 32; ++dk) {
            float wv0 = Wt[dk * 256 + te];
            float wv1 = Wt[dk * 256 + te + 64];
            float wv2 = Wt[dk * 256 + te + 128];
            float wv3 = Wt[dk * 256 + te + 192];
            #pragma unroll
            for (int i = 0; i < 16; ++i) {
                float xv = xs[(tp * 16 + i) * 32 + dk];
                acc[i][0] += xv * wv0;
                acc[i][1] += xv * wv1;
                acc[i][2] += xv * wv2;
                acc[i][3] += xv * wv3;
            }
        }
        __syncthreads();
    }
    #pragma unroll
    for (int i = 0; i < 16; ++i) {
        int pos = pos0 + tp * 16 + i;
        uraw[pos * 128 + te]       = acc[i][0];
        uraw[pos * 128 + te + 64]  = acc[i][1];
        z[pos * 128 + te]          = acc[i][2];
        z[pos * 128 + te + 64]     = acc[i][3];
    }
}

// ---------------- K4: causal conv1d + silu -> u ; x_proj ; delta=softplus(dt@dtw+b) ; Bm,Cm ----
__global__ __launch_bounds__(128) void k4_convproj(const float* __restrict__ uraw,
                                                   const float* __restrict__ cw,
                                                   const float* __restrict__ cb,
                                                   const float* __restrict__ xpw,
                                                   const float* __restrict__ dtw,
                                                   const float* __restrict__ dtb,
                                                   float* __restrict__ u,
                                                   float* __restrict__ delta,
                                                   float* __restrict__ Bm,
                                                   float* __restrict__ Cm) {
    __shared__ float xpwT[128 * 24];  // [d][e]
    __shared__ float usx[16 * 128];   // [q][d]
    __shared__ float xdb[16 * 24];    // [q][e]
    int d = threadIdx.x;
    #pragma unroll
    for (int e = 0; e < 24; ++e) xpwT[d * 24 + e] = xpw[e * 128 + d];
    float cw0 = cw[d * 3 + 0], cw1 = cw[d * 3 + 1], cw2 = cw[d * 3 + 2], cbr = cb[d];
    float dtwr[8];
    #pragma unroll
    for (int r = 0; r < 8; ++r) dtwr[r] = dtw[d * 8 + r];
    float dtbr = dtb[d];

    int gpos0 = blockIdx.x * 16;     // global position (b*L + l0)
    int l0 = gpos0 & 4095;
    int base = gpos0 * 128 + d;

    float ur[18];
    ur[0] = (l0 >= 2) ? uraw[base - 256] : 0.f;
    ur[1] = (l0 >= 1) ? uraw[base - 128] : 0.f;
    #pragma unroll
    for (int q = 0; q < 16; ++q) ur[2 + q] = uraw[base + q * 128];
    #pragma unroll
    for (int q = 0; q < 16; ++q) {
        float uc = ur[q] * cw0 + ur[q + 1] * cw1 + ur[q + 2] * cw2 + cbr;
        float us = siluf(uc);
        u[base + q * 128] = us;
        usx[q * 128 + d] = us;
    }
    __syncthreads();
    #pragma unroll
    for (int k = 0; k < 3; ++k) {   // 384 dot-products over 128 threads
        int task = k * 128 + d;
        int p = task / 24;
        int e = task - p * 24;
        const float* ux = &usx[p * 128];
        float acc = 0.f;
        for (int dd = 0; dd < 128; ++dd) acc += ux[dd] * xpwT[dd * 24 + e];
        xdb[p * 24 + e] = acc;
    }
    __syncthreads();
    #pragma unroll
    for (int q = 0; q < 16; ++q) {
        float dt = dtbr;
        #pragma unroll
        for (int r = 0; r < 8; ++r) dt += xdb[q * 24 + r] * dtwr[r];
        delta[base + q * 128] = softplusf(dt);
    }
    #pragma unroll
    for (int k = 0; k < 2; ++k) {
        int idx = k * 128 + d;      // 0..255 = 16 pos * 16 vals
        int q = idx >> 4;
        int j = idx & 15;
        float v = xdb[q * 24 + 8 + j];
        int lpos = gpos0 + q;
        if (j < 8) Bm[lpos * 8 + j] = v;
        else       Cm[lpos * 8 + (j - 8)] = v;
    }
}

// ---------------- K5: scan phase 1 (per-chunk prod(a) and local state) ----------------
__global__ __launch_bounds__(128) void k5_scan1(const float* __restrict__ delta,
                                                const float* __restrict__ u,
                                                const float* __restrict__ Bm,
                                                const float* __restrict__ A_log,
                                                float* __restrict__ cA,
                                                float* __restrict__ cB) {
    int d = threadIdx.x;
    int bc = blockIdx.x;            // b*NC_ + c
    int b = bc >> 7, c = bc & 127;
    float Ar[8];
    #pragma unroll
    for (int n = 0; n < 8; ++n) Ar[n] = -__expf(A_log[d * 8 + n]);
    float h[8], ap[8];
    #pragma unroll
    for (int n = 0; n < 8; ++n) { h[n] = 0.f; ap[n] = 1.f; }
    int l0 = c * S_;
    int base  = (b * L_ + l0) * 128 + d;
    int bbase = (b * L_ + l0) * 8;
    for (int s = 0; s < S_; ++s) {
        float dl = delta[base + s * 128];
        float uv = u[base + s * 128];
        float du = dl * uv;
        float4 bm0 = *(const float4*)&Bm[bbase + s * 8];
        float4 bm1 = *(const float4*)&Bm[bbase + s * 8 + 4];
        float a;
        a = __expf(dl * Ar[0]); ap[0] *= a; h[0] = a * h[0] + du * bm0.x;
        a = __expf(dl * Ar[1]); ap[1] *= a; h[1] = a * h[1] + du * bm0.y;
        a = __expf(dl * Ar[2]); ap[2] *= a; h[2] = a * h[2] + du * bm0.z;
        a = __expf(dl * Ar[3]); ap[3] *= a; h[3] = a * h[3] + du * bm0.w;
        a = __expf(dl * Ar[4]); ap[4] *= a; h[4] = a * h[4] + du * bm1.x;
        a = __expf(dl * Ar[5]); ap[5] *= a; h[5] = a * h[5] + du * bm1.y;
        a = __expf(dl * Ar[6]); ap[6] *= a; h[6] = a * h[6] + du * bm1.z;
        a = __expf(dl * Ar[7]); ap[7] *= a; h[7] = a * h[7] + du * bm1.w;
    }
    int obase = (bc * 128 + d) * 8;
    *(float4*)&cA[obase]     = make_float4(ap[0], ap[1], ap[2], ap[3]);
    *(float4*)&cA[obase + 4] = make_float4(ap[4], ap[5], ap[6], ap[7]);
    *(float4*)&cB[obase]     = make_float4(h[0], h[1], h[2], h[3]);
    *(float4*)&cB[obase + 4] = make_float4(h[4], h[5], h[6], h[7]);
}

// ---------------- K6: scan phase 2 (inter-chunk scan -> carries) ----------------
__global__ __launch_bounds__(128) void k6_scan2(const float* __restrict__ cA,
                                                const float* __restrict__ cB,
                                                float* __restrict__ carry) {
    int b = blockIdx.x >> 3;
    int slice = blockIdx.x & 7;
    int dn = slice * 128 + threadIdx.x;   // 0..1023 = d*8+n
    float h = 0.f;
    for (int c = 0; c < NC_; ++c) {
        int idx = (b * NC_ + c) * 1024 + dn;
        float a  = cA[idx];
        float bv = cB[idx];
        carry[idx] = h;
        h = a * h + bv;
    }
}

// ---------------- K7: scan phase 3 (replay with carry, emit y=(h.C + u*D)*silu(z)) --------
__global__ __launch_bounds__(128) void k7_scan3(const float* __restrict__ delta,
                                                const float* __restrict__ u,
                                                const float* __restrict__ Bm,
                                                const float* __restrict__ Cm,
                                                const float* __restrict__ z,
                                                const float* __restrict__ A_log,
                                                const float* __restrict__ Dp,
                                                const float* __restrict__ carry,
                                                float* __restrict__ y) {
    int d = threadIdx.x;
    int bc = blockIdx.x;
    int b = bc >> 7, c = bc & 127;
    float Ar[8];
    #pragma unroll
    for (int n = 0; n < 8; ++n) Ar[n] = -__expf(A_log[d * 8 + n]);
    float Dpr = Dp[d];
    int cbase = (bc * 128 + d) * 8;
    float4 h0 = *(const float4*)&carry[cbase];
    float4 h1 = *(const float4*)&carry[cbase + 4];
    float h[8] = {h0.x, h0.y, h0.z, h0.w, h1.x, h1.y, h1.z, h1.w};
    int l0 = c * S_;
    int base  = (b * L_ + l0) * 128 + d;
    int bbase = (b * L_ + l0) * 8;
    for (int s = 0; s < S_; ++s) {
        float dl = delta[base + s * 128];
        float uv = u[base + s * 128];
        float zv = z[base + s * 128];
        float du = dl * uv;
        float4 bm0 = *(const float4*)&Bm[bbase + s * 8];
        float4 bm1 = *(const float4*)&Bm[bbase + s * 8 + 4];
        float4 cm0 = *(const float4*)&Cm[bbase + s * 8];
        float4 cm1 = *(const float4*)&Cm[bbase + s * 8 + 4];
        float a;
        a = __expf(dl * Ar[0]); h[0] = a * h[0] + du * bm0.x;
        a = __expf(dl * Ar[1]); h[1] = a * h[1] + du * bm0.y;
        a = __expf(dl * Ar[2]); h[2] = a * h[2] + du * bm0.z;
        a = __expf(dl * Ar[3]); h[3] = a * h[3] + du * bm0.w;
        a = __expf(dl * Ar[4]); h[4] = a * h[4] + du * bm1.x;
        a = __expf(dl * Ar[5]); h[5] = a * h[5] + du * bm1.y;
        a = __expf(dl * Ar[6]); h[6] = a * h[6] + du * bm1.z;
        a = __expf(dl * Ar[7]); h[7] = a * h[7] + du * bm1.w;
        float yv = h[0] * cm0.x + h[1] * cm0.y + h[2] * cm0.z + h[3] * cm0.w
                 + h[4] * cm1.x + h[5] * cm1.y + h[6] * cm1.z + h[7] * cm1.w;
        yv = (yv + uv * Dpr) * siluf(zv);
        y[base + s * 128] = yv;
    }
}

// ---------------- K8: out_proj GEMM + LayerNorm + *x2s + grouped 1x1 (wout) -> out --------
// block 256 thr: 64 positions; thread: 8 pos (tp=t>>5) x 4 outputs (te=t&31, e=te+32j)
__global__ __launch_bounds__(256) void k8_outfuse(const float* __restrict__ y,
                                                  const float* __restrict__ OW,
                                                  const float* __restrict__ gamma,
                                                  const float* __restrict__ beta,
                                                  const float* __restrict__ x2s,
                                                  const float* __restrict__ wout,
                                                  float* __restrict__ out) {
    __shared__ float wt[32 * 128];   // woutT: wt[i*128+c] = wout[(c>>5)*1024+(c&31)*32+i]
    __shared__ float un[8192];       // ys [0..2047], OWt [2048..6143]; later xfs [0..8191]
    int t  = threadIdx.x;
    int te = t & 31, tp = t >> 5;
    for (int idx = t; idx < 4096; idx += 256) {
        int i = idx >> 7, c = idx & 127;
        wt[idx] = wout[(c >> 5) * 1024 + (c & 31) * 32 + i];
    }
    float gr[4], br[4];
    #pragma unroll
    for (int j = 0; j < 4; ++j) { gr[j] = gamma[te + 32 * j]; br[j] = beta[te + 32 * j]; }

    float acc[8][4];
    #pragma unroll
    for (int i = 0; i < 8; ++i)
        #pragma unroll
        for (int j = 0; j < 4; ++j) acc[i][j] = 0.f;

    int pos0 = blockIdx.x * 64;
    float* ys  = un;
    float* OWt = un + 2048;
    for (int kb = 0; kb < 4; ++kb) {
        #pragma unroll
        for (int q = 0; q < 2; ++q) {
            int fi = t * 2 + q;
            int p = fi >> 3, dk4 = fi & 7;
            float4 v = *(const float4*)&y[(pos0 + p) * 128 + kb * 32 + dk4 * 4];
            *(float4*)&ys[p * 32 + dk4 * 4] = v;
        }
        {
            int e = t & 127, half = t >> 7;
            #pragma unroll
            for (int q = 0; q < 4; ++q) {
                int dk = half * 16 + q * 4;
                float4 v = *(const float4*)&OW[e * 128 + kb * 32 + dk];
                OWt[(dk + 0) * 128 + e] = v.x;
                OWt[(dk + 1) * 128 + e] = v.y;
                OWt[(dk + 2) * 128 + e] = v.z;
                OWt[(dk + 3) * 128 + e] = v.w;
            }
        }
        __syncthreads();
        #pragma unroll 4
        for (int dk = 0; dk < 32; ++dk) {
            float wv0 = OWt[dk * 128 + te];
            float wv1 = OWt[dk * 128 + te + 32];
            float wv2 = OWt[dk * 128 + te + 64];
            float wv3 = OWt[dk * 128 + te + 96];
            #pragma unroll
            for (int i = 0; i < 8; ++i) {
                float xv = ys[(tp * 8 + i) * 32 + dk];
                acc[i][0] += xv * wv0;
                acc[i][1] += xv * wv1;
                acc[i][2] += xv * wv2;
                acc[i][3] += xv * wv3;
            }
        }
        __syncthreads();
    }
    // LayerNorm over the 128 channels of each position (spread over a 32-lane half-wave)
    float mu[8], rstd[8];
    #pragma unroll
    for (int i = 0; i < 8; ++i) {
        float s  = acc[i][0] + acc[i][1] + acc[i][2] + acc[i][3];
        float s2 = acc[i][0] * acc[i][0] + acc[i][1] * acc[i][1]
                 + acc[i][2] * acc[i][2] + acc[i][3] * acc[i][3];
        #pragma unroll
        for (int off = 16; off >= 1; off >>= 1) {
            s  += __shfl_xor(s, off, 64);
            s2 += __shfl_xor(s2, off, 64);
        }
        float m = s * (1.f / 128.f);
        float var = s2 * (1.f / 128.f) - m * m;
        mu[i] = m;
        rstd[i] = rsqrtf(var + 1e-5f);
    }
    float* xfs = un;   // reuse union region
    #pragma unroll
    for (int i = 0; i < 8; ++i) {
        int pos = pos0 + tp * 8 + i;
        #pragma unroll
        for (int j = 0; j < 4; ++j) {
            int e = te + 32 * j;
            float v = (acc[i][j] - mu[i]) * rstd[i] * gr[j] + br[j];
            v *= x2s[pos * 128 + e];
            xfs[(tp * 8 + i) * 128 + e] = v;
        }
    }
    __syncthreads();
    // final grouped 1x1 with wout: c = 32*j + te (g=j, o=te)
    #pragma unroll
    for (int i = 0; i < 8; ++i) {
        int pos = pos0 + tp * 8 + i;
        const float* xr = &xfs[(tp * 8 + i) * 128];
        float a2[4] = {0.f, 0.f, 0.f, 0.f};
        for (int ii = 0; ii < 32; ++ii) {
            #pragma unroll
            for (int j = 0; j < 4; ++j)
                a2[j] += xr[j * 32 + ii] * wt[ii * 128 + 32 * j + te];
        }
        #pragma unroll
        for (int j = 0; j < 4; ++j) out[pos * 128 + 32 * j + te] = a2[j];
    }
}

extern "C" void kernel_launch(void* const* d_in, const int* in_sizes, int n_in,
                              void* d_out, int out_size, void* d_ws, size_t ws_size,
                              hipStream_t stream) {
    (void)in_sizes; (void)n_in; (void)out_size; (void)ws_size;
    const float* x         = (const float*)d_in[0];
    const float* w1        = (const float*)d_in[1];
    const float* dw        = (const float*)d_in[2];
    const float* in_proj_w = (const float*)d_in[3];
    const float* conv1d_w  = (const float*)d_in[4];
    const float* conv1d_b  = (const float*)d_in[5];
    const float* x_proj_w  = (const float*)d_in[6];
    const float* dt_proj_w = (const float*)d_in[7];
    const float* dt_proj_b = (const float*)d_in[8];
    const float* A_log     = (const float*)d_in[9];
    const float* D_param   = (const float*)d_in[10];
    const float* out_proj_w= (const float*)d_in[11];
    const float* gamma     = (const float*)d_in[12];
    const float* beta      = (const float*)d_in[13];
    const float* w2        = (const float*)d_in[14];
    const float* wout      = (const float*)d_in[15];
    float* out = (float*)d_out;

    float* ws   = (float*)d_ws;
    float* t1   = ws;                 // NB_ ; reused as u after K2
    float* x2s  = ws + (size_t)NB_;
    float* x1c  = ws + 2 * (size_t)NB_;  // reused as delta after K3
    float* uraw = ws + 3 * (size_t)NB_;  // reused as y after K4
    float* z    = ws + 4 * (size_t)NB_;
    float* Bm   = ws + 5 * (size_t)NB_;        // NPOS_*8
    float* Cm   = Bm + (size_t)NPOS_ * 8;      // NPOS_*8
    float* cA   = Cm + (size_t)NPOS_ * 8;      // 1048576
    float* cB   = cA + 1048576;
    float* carry= cB + 1048576;
    float* u     = t1;
    float* delta = x1c;
    float* yb    = uraw;

    k1_g1x1<<<512, 128, 0, stream>>>(x, w1, w2, t1, x2s);
    k2_dwconv<<<2048, 128, 0, stream>>>(t1, dw, x1c);
    k3_inproj<<<512, 256, 0, stream>>>(x1c, in_proj_w, uraw, z);
    k4_convproj<<<2048, 128, 0, stream>>>(uraw, conv1d_w, conv1d_b, x_proj_w,
                                          dt_proj_w, dt_proj_b, u, delta, Bm, Cm);
    k5_scan1<<<1024, 128, 0, stream>>>(delta, u, Bm, A_log, cA, cB);
    k6_scan2<<<64, 128, 0, stream>>>(cA, cB, carry);
    k7_scan3<<<1024, 128, 0, stream>>>(delta, u, Bm, Cm, z, A_log, D_param, carry, yb);
    k8_outfuse<<<512, 256, 0, stream>>>(yb, out_proj_w, gamma, beta, x2s, wout, out);
}

// Round 2
// 288.004 us; speedup vs baseline: 1.2674x; 1.2674x over previous
//
#include <hip/hip_runtime.h>
#include <math.h>

#define B_    8
#define C_    128
#define D_    128
#define L_    4096
#define NPOS_ 32768
#define NC_   128
#define S_    32
#define NB_   4194304      // NPOS_*128 elements
#define MFL_  1048576

typedef __attribute__((ext_vector_type(8))) short short8;
typedef __attribute__((ext_vector_type(4))) float f32x4;

__device__ __forceinline__ float siluf(float x) { return x / (1.f + __expf(-x)); }
__device__ __forceinline__ float softplusf(float x) {
    if (x > 20.f) return x;
    return log1pf(__expf(x));
}
__device__ __forceinline__ unsigned short f2bf(float f) {
    unsigned int u = __float_as_uint(f);
    u = (u + 0x7FFFu + ((u >> 16) & 1u)) >> 16;
    return (unsigned short)u;
}

// ---------------- K0: convert in_proj_w (32768) and out_proj_w (16384) to bf16 ----------------
__global__ __launch_bounds__(256) void k0_cvt(const float* __restrict__ inW,
                                              const float* __restrict__ OW,
                                              unsigned short* __restrict__ inWb,
                                              unsigned short* __restrict__ OWb) {
    int idx = blockIdx.x * 256 + threadIdx.x;
    for (int i = idx; i < 49152; i += 12288) {
        if (i < 32768) inWb[i] = f2bf(inW[i]);
        else           OWb[i - 32768] = f2bf(OW[i - 32768]);
    }
}

// ---------------- K1: grouped 1x1 (w1)->t1 ; silu(grouped 1x1 (w2))->x2s ----------------
// weights in registers; x via LDS b128 broadcast reads. 256 thr, 64 pos/block.
__global__ __launch_bounds__(256) void k1_g1x1(const float* __restrict__ x,
                                               const float* __restrict__ w1,
                                               const float* __restrict__ w2,
                                               float* __restrict__ t1,
                                               float* __restrict__ x2s) {
    __shared__ float xs[16 * 128];
    int t = threadIdx.x;
    int d = t & 127, ph = t >> 7;
    int g = d >> 5, o = d & 31;
    float w1r[32], w2r[32];
    #pragma unroll
    for (int i = 0; i < 32; ++i) {
        w1r[i] = w1[g * 1024 + o * 32 + i];
        w2r[i] = w2[g * 1024 + o * 32 + i];
    }
    int pos0 = blockIdx.x * 64;
    for (int it = 0; it < 4; ++it) {
        int p0 = pos0 + it * 16;
        #pragma unroll
        for (int q = 0; q < 2; ++q) {
            int fi = t * 2 + q;    // 0..511 float4s
            *(float4*)&xs[fi * 4] = *(const float4*)&x[p0 * 128 + fi * 4];
        }
        __syncthreads();
        #pragma unroll
        for (int q = 0; q < 8; ++q) {
            int pl = ph * 8 + q;
            float a1 = 0.f, a2 = 0.f;
            const float* xr = &xs[pl * 128 + g * 32];
            #pragma unroll
            for (int i4 = 0; i4 < 8; ++i4) {
                float4 xv = *(const float4*)&xr[i4 * 4];
                a1 += xv.x * w1r[i4*4] + xv.y * w1r[i4*4+1] + xv.z * w1r[i4*4+2] + xv.w * w1r[i4*4+3];
                a2 += xv.x * w2r[i4*4] + xv.y * w2r[i4*4+1] + xv.z * w2r[i4*4+2] + xv.w * w2r[i4*4+3];
            }
            int pos = p0 + pl;
            t1[pos * 128 + d]  = a1;
            x2s[pos * 128 + d] = siluf(a2);
        }
        __syncthreads();
    }
}

// ---------------- K2: depthwise 3x3 SAME + silu -> bf16 ----------------
__global__ __launch_bounds__(128) void k2_dwconv(const float* __restrict__ t1,
                                                 const float* __restrict__ dw,
                                                 unsigned short* __restrict__ x1cb) {
    int d = threadIdx.x;
    float dwr[9];
    #pragma unroll
    for (int k = 0; k < 9; ++k) dwr[k] = dw[k * 128 + d];
    int bid = blockIdx.x;          // 2048
    int wq = bid & 3;
    int h  = (bid >> 2) & 63;
    int b  = bid >> 8;
    int w0 = wq * 16;
    for (int wi = 0; wi < 16; ++wi) {
        int w = w0 + wi;
        float acc = 0.f;
        #pragma unroll
        for (int kh = -1; kh <= 1; ++kh) {
            int hh = h + kh;
            if (hh < 0 || hh > 63) continue;
            #pragma unroll
            for (int kw = -1; kw <= 1; ++kw) {
                int ww = w + kw;
                if (ww < 0 || ww > 63) continue;
                acc += t1[((b * 64 + hh) * 64 + ww) * 128 + d] * dwr[(kh + 1) * 3 + (kw + 1)];
            }
        }
        x1cb[((b * 64 + h) * 64 + w) * 128 + d] = f2bf(siluf(acc));
    }
}

// ---------------- K3: in_proj via bf16 MFMA: [128 pos x 128 out] tile, K=128 in 2 chunks ----
__global__ __launch_bounds__(256) void k3_mfma(const unsigned short* __restrict__ Abf,
                                               const unsigned short* __restrict__ Bbf,
                                               float* __restrict__ uraw,
                                               float* __restrict__ z) {
    __shared__ unsigned short Al[128 * 72];
    __shared__ unsigned short Bl[128 * 72];
    int t = threadIdx.x;
    int mtile = blockIdx.x >> 1, ntile = blockIdx.x & 1;
    int pos0 = mtile * 128, n0g = ntile * 128;
    int lane = t & 63, wv = t >> 6;
    int m0 = (wv & 1) * 64, n0w = (wv >> 1) * 64;
    int lanem = lane & 15, laneq = lane >> 4;
    f32x4 acc[4][4];
    #pragma unroll
    for (int i = 0; i < 4; ++i)
        #pragma unroll
        for (int j = 0; j < 4; ++j) acc[i][j] = (f32x4){0.f, 0.f, 0.f, 0.f};
    for (int kc = 0; kc < 2; ++kc) {
        #pragma unroll
        for (int q = 0; q < 4; ++q) {
            int c = t + q * 256;           // 0..1023: row = c>>3, col8 = c&7
            int row = c >> 3, col = c & 7;
            *(int4*)&Al[row * 72 + col * 8] = *(const int4*)&Abf[(pos0 + row) * 128 + kc * 64 + col * 8];
            *(int4*)&Bl[row * 72 + col * 8] = *(const int4*)&Bbf[(n0g + row) * 128 + kc * 64 + col * 8];
        }
        __syncthreads();
        #pragma unroll
        for (int ks = 0; ks < 2; ++ks) {
            short8 af[4], bfr[4];
            #pragma unroll
            for (int mi = 0; mi < 4; ++mi)
                af[mi] = *(const short8*)&Al[(m0 + mi * 16 + lanem) * 72 + ks * 32 + laneq * 8];
            #pragma unroll
            for (int ni = 0; ni < 4; ++ni)
                bfr[ni] = *(const short8*)&Bl[(n0w + ni * 16 + lanem) * 72 + ks * 32 + laneq * 8];
            #pragma unroll
            for (int mi = 0; mi < 4; ++mi)
                #pragma unroll
                for (int ni = 0; ni < 4; ++ni)
                    acc[mi][ni] = __builtin_amdgcn_mfma_f32_16x16x32_bf16(af[mi], bfr[ni], acc[mi][ni], 0, 0, 0);
        }
        __syncthreads();
    }
    float* dst = ntile ? z : uraw;
    #pragma unroll
    for (int mi = 0; mi < 4; ++mi)
        #pragma unroll
        for (int ni = 0; ni < 4; ++ni)
            #pragma unroll
            for (int r = 0; r < 4; ++r) {
                int m = pos0 + m0 + mi * 16 + laneq * 4 + r;
                int n = n0w + ni * 16 + lanem;
                dst[m * 128 + n] = acc[mi][ni][r];
            }
}

// ---------------- K4: causal conv1d+silu -> u ; x_proj ; delta ; Bm,Cm ----------------
__global__ __launch_bounds__(128) void k4_convproj(const float* __restrict__ uraw,
                                                   const float* __restrict__ cw,
                                                   const float* __restrict__ cb,
                                                   const float* __restrict__ xpw,
                                                   const float* __restrict__ dtw,
                                                   const float* __restrict__ dtb,
                                                   float* __restrict__ u,
                                                   float* __restrict__ delta,
                                                   float* __restrict__ Bm,
                                                   float* __restrict__ Cm) {
    __shared__ float xpwT[128 * 24];
    __shared__ float usx[16 * 128];
    __shared__ float xdb[16 * 24];
    int d = threadIdx.x;
    #pragma unroll
    for (int e = 0; e < 24; ++e) xpwT[d * 24 + e] = xpw[e * 128 + d];
    float cw0 = cw[d * 3 + 0], cw1 = cw[d * 3 + 1], cw2 = cw[d * 3 + 2], cbr = cb[d];
    float dtwr[8];
    #pragma unroll
    for (int r = 0; r < 8; ++r) dtwr[r] = dtw[d * 8 + r];
    float dtbr = dtb[d];

    int gpos0 = blockIdx.x * 16;
    int l0 = gpos0 & 4095;
    int base = gpos0 * 128 + d;

    float ur[18];
    ur[0] = (l0 >= 2) ? uraw[base - 256] : 0.f;
    ur[1] = (l0 >= 1) ? uraw[base - 128] : 0.f;
    #pragma unroll
    for (int q = 0; q < 16; ++q) ur[2 + q] = uraw[base + q * 128];
    #pragma unroll
    for (int q = 0; q < 16; ++q) {
        float uc = ur[q] * cw0 + ur[q + 1] * cw1 + ur[q + 2] * cw2 + cbr;
        float us = siluf(uc);
        u[base + q * 128] = us;
        usx[q * 128 + d] = us;
    }
    __syncthreads();
    #pragma unroll
    for (int k = 0; k < 3; ++k) {
        int task = k * 128 + d;
        int p = task / 24;
        int e = task - p * 24;
        const float* ux = &usx[p * 128];
        float acc = 0.f;
        for (int dd = 0; dd < 128; ++dd) acc += ux[dd] * xpwT[dd * 24 + e];
        xdb[p * 24 + e] = acc;
    }
    __syncthreads();
    #pragma unroll
    for (int q = 0; q < 16; ++q) {
        float dt = dtbr;
        #pragma unroll
        for (int r = 0; r < 8; ++r) dt += xdb[q * 24 + r] * dtwr[r];
        delta[base + q * 128] = softplusf(dt);
    }
    #pragma unroll
    for (int k = 0; k < 2; ++k) {
        int idx = k * 128 + d;
        int q = idx >> 4;
        int j = idx & 15;
        float v = xdb[q * 24 + 8 + j];
        int lpos = gpos0 + q;
        if (j < 8) Bm[lpos * 8 + j] = v;
        else       Cm[lpos * 8 + (j - 8)] = v;
    }
}

// ---------------- K5: scan phase 1 ----------------
__global__ __launch_bounds__(128) void k5_scan1(const float* __restrict__ delta,
                                                const float* __restrict__ u,
                                                const float* __restrict__ Bm,
                                                const float* __restrict__ A_log,
                                                float* __restrict__ cA,
                                                float* __restrict__ cB) {
    int d = threadIdx.x;
    int bc = blockIdx.x;
    int b = bc >> 7, c = bc & 127;
    float Ar[8];
    #pragma unroll
    for (int n = 0; n < 8; ++n) Ar[n] = -__expf(A_log[d * 8 + n]);
    float h[8], ap[8];
    #pragma unroll
    for (int n = 0; n < 8; ++n) { h[n] = 0.f; ap[n] = 1.f; }
    int l0 = c * S_;
    int base  = (b * L_ + l0) * 128 + d;
    int bbase = (b * L_ + l0) * 8;
    for (int s = 0; s < S_; ++s) {
        float dl = delta[base + s * 128];
        float uv = u[base + s * 128];
        float du = dl * uv;
        float4 bm0 = *(const float4*)&Bm[bbase + s * 8];
        float4 bm1 = *(const float4*)&Bm[bbase + s * 8 + 4];
        float a;
        a = __expf(dl * Ar[0]); ap[0] *= a; h[0] = a * h[0] + du * bm0.x;
        a = __expf(dl * Ar[1]); ap[1] *= a; h[1] = a * h[1] + du * bm0.y;
        a = __expf(dl * Ar[2]); ap[2] *= a; h[2] = a * h[2] + du * bm0.z;
        a = __expf(dl * Ar[3]); ap[3] *= a; h[3] = a * h[3] + du * bm0.w;
        a = __expf(dl * Ar[4]); ap[4] *= a; h[4] = a * h[4] + du * bm1.x;
        a = __expf(dl * Ar[5]); ap[5] *= a; h[5] = a * h[5] + du * bm1.y;
        a = __expf(dl * Ar[6]); ap[6] *= a; h[6] = a * h[6] + du * bm1.z;
        a = __expf(dl * Ar[7]); ap[7] *= a; h[7] = a * h[7] + du * bm1.w;
    }
    int obase = (bc * 128 + d) * 8;
    *(float4*)&cA[obase]     = make_float4(ap[0], ap[1], ap[2], ap[3]);
    *(float4*)&cA[obase + 4] = make_float4(ap[4], ap[5], ap[6], ap[7]);
    *(float4*)&cB[obase]     = make_float4(h[0], h[1], h[2], h[3]);
    *(float4*)&cB[obase + 4] = make_float4(h[4], h[5], h[6], h[7]);
}

// ---------------- K6: scan phase 2 ----------------
__global__ __launch_bounds__(128) void k6_scan2(const float* __restrict__ cA,
                                                const float* __restrict__ cB,
                                                float* __restrict__ carry) {
    int b = blockIdx.x >> 3;
    int slice = blockIdx.x & 7;
    int dn = slice * 128 + threadIdx.x;
    float h = 0.f;
    for (int c = 0; c < NC_; ++c) {
        int idx = (b * NC_ + c) * 1024 + dn;
        float a  = cA[idx];
        float bv = cB[idx];
        carry[idx] = h;
        h = a * h + bv;
    }
}

// ---------------- K7: scan phase 3, emit y (bf16) ----------------
__global__ __launch_bounds__(128) void k7_scan3(const float* __restrict__ delta,
                                                const float* __restrict__ u,
                                                const float* __restrict__ Bm,
                                                const float* __restrict__ Cm,
                                                const float* __restrict__ z,
                                                const float* __restrict__ A_log,
                                                const float* __restrict__ Dp,
                                                const float* __restrict__ carry,
                                                unsigned short* __restrict__ ybf) {
    int d = threadIdx.x;
    int bc = blockIdx.x;
    int b = bc >> 7, c = bc & 127;
    float Ar[8];
    #pragma unroll
    for (int n = 0; n < 8; ++n) Ar[n] = -__expf(A_log[d * 8 + n]);
    float Dpr = Dp[d];
    int cbase = (bc * 128 + d) * 8;
    float4 h0 = *(const float4*)&carry[cbase];
    float4 h1 = *(const float4*)&carry[cbase + 4];
    float h[8] = {h0.x, h0.y, h0.z, h0.w, h1.x, h1.y, h1.z, h1.w};
    int l0 = c * S_;
    int base  = (b * L_ + l0) * 128 + d;
    int bbase = (b * L_ + l0) * 8;
    for (int s = 0; s < S_; ++s) {
        float dl = delta[base + s * 128];
        float uv = u[base + s * 128];
        float zv = z[base + s * 128];
        float du = dl * uv;
        float4 bm0 = *(const float4*)&Bm[bbase + s * 8];
        float4 bm1 = *(const float4*)&Bm[bbase + s * 8 + 4];
        float4 cm0 = *(const float4*)&Cm[bbase + s * 8];
        float4 cm1 = *(const float4*)&Cm[bbase + s * 8 + 4];
        float a;
        a = __expf(dl * Ar[0]); h[0] = a * h[0] + du * bm0.x;
        a = __expf(dl * Ar[1]); h[1] = a * h[1] + du * bm0.y;
        a = __expf(dl * Ar[2]); h[2] = a * h[2] + du * bm0.z;
        a = __expf(dl * Ar[3]); h[3] = a * h[3] + du * bm0.w;
        a = __expf(dl * Ar[4]); h[4] = a * h[4] + du * bm1.x;
        a = __expf(dl * Ar[5]); h[5] = a * h[5] + du * bm1.y;
        a = __expf(dl * Ar[6]); h[6] = a * h[6] + du * bm1.z;
        a = __expf(dl * Ar[7]); h[7] = a * h[7] + du * bm1.w;
        float yv = h[0] * cm0.x + h[1] * cm0.y + h[2] * cm0.z + h[3] * cm0.w
                 + h[4] * cm1.x + h[5] * cm1.y + h[6] * cm1.z + h[7] * cm1.w;
        yv = (yv + uv * Dpr) * siluf(zv);
        ybf[base + s * 128] = f2bf(yv);
    }
}

// ---------------- K8a: out_proj via bf16 MFMA -> xz fp32 ----------------
__global__ __launch_bounds__(256) void k8a_mfma(const unsigned short* __restrict__ Abf,
                                                const unsigned short* __restrict__ Bbf,
                                                float* __restrict__ xz) {
    __shared__ unsigned short Al[128 * 72];
    __shared__ unsigned short Bl[128 * 72];
    int t = threadIdx.x;
    int pos0 = blockIdx.x * 128;
    int lane = t & 63, wv = t >> 6;
    int m0 = (wv & 1) * 64, n0w = (wv >> 1) * 64;
    int lanem = lane & 15, laneq = lane >> 4;
    f32x4 acc[4][4];
    #pragma unroll
    for (int i = 0; i < 4; ++i)
        #pragma unroll
        for (int j = 0; j < 4; ++j) acc[i][j] = (f32x4){0.f, 0.f, 0.f, 0.f};
    for (int kc = 0; kc < 2; ++kc) {
        #pragma unroll
        for (int q = 0; q < 4; ++q) {
            int c = t + q * 256;
            int row = c >> 3, col = c & 7;
            *(int4*)&Al[row * 72 + col * 8] = *(const int4*)&Abf[(pos0 + row) * 128 + kc * 64 + col * 8];
            *(int4*)&Bl[row * 72 + col * 8] = *(const int4*)&Bbf[row * 128 + kc * 64 + col * 8];
        }
        __syncthreads();
        #pragma unroll
        for (int ks = 0; ks < 2; ++ks) {
            short8 af[4], bfr[4];
            #pragma unroll
            for (int mi = 0; mi < 4; ++mi)
                af[mi] = *(const short8*)&Al[(m0 + mi * 16 + lanem) * 72 + ks * 32 + laneq * 8];
            #pragma unroll
            for (int ni = 0; ni < 4; ++ni)
                bfr[ni] = *(const short8*)&Bl[(n0w + ni * 16 + lanem) * 72 + ks * 32 + laneq * 8];
            #pragma unroll
            for (int mi = 0; mi < 4; ++mi)
                #pragma unroll
                for (int ni = 0; ni < 4; ++ni)
                    acc[mi][ni] = __builtin_amdgcn_mfma_f32_16x16x32_bf16(af[mi], bfr[ni], acc[mi][ni], 0, 0, 0);
        }
        __syncthreads();
    }
    #pragma unroll
    for (int mi = 0; mi < 4; ++mi)
        #pragma unroll
        for (int ni = 0; ni < 4; ++ni)
            #pragma unroll
            for (int r = 0; r < 4; ++r) {
                int m = pos0 + m0 + mi * 16 + laneq * 4 + r;
                int n = n0w + ni * 16 + lanem;
                xz[m * 128 + n] = acc[mi][ni][r];
            }
}

// ---------------- K8b: LayerNorm + *x2s + grouped 1x1 (wout) -> out ----------------
// 256 thr, 32 pos/block, grid 1024. te=t&31 (4 ch), tp=t>>5 (4 pos).
__global__ __launch_bounds__(256) void k8b_epi(const float* __restrict__ xz,
                                               const float* __restrict__ gamma,
                                               const float* __restrict__ beta,
                                               const float* __restrict__ x2s,
                                               const float* __restrict__ wout,
                                               float* __restrict__ out) {
    __shared__ float wt[32 * 128];
    __shared__ float xfs[32 * 132];
    int t  = threadIdx.x;
    int te = t & 31, tp = t >> 5;
    for (int idx = t; idx < 4096; idx += 256) {
        int i = idx >> 7, c = idx & 127;
        wt[idx] = wout[(c >> 5) * 1024 + (c & 31) * 32 + i];
    }
    float gr[4], br[4];
    #pragma unroll
    for (int j = 0; j < 4; ++j) { gr[j] = gamma[te + 32 * j]; br[j] = beta[te + 32 * j]; }

    int pos0 = blockIdx.x * 32;
    float acc[4][4];
    #pragma unroll
    for (int i = 0; i < 4; ++i) {
        int pos = pos0 + tp * 4 + i;
        #pragma unroll
        for (int j = 0; j < 4; ++j) acc[i][j] = xz[pos * 128 + te + 32 * j];
    }
    #pragma unroll
    for (int i = 0; i < 4; ++i) {
        float s  = acc[i][0] + acc[i][1] + acc[i][2] + acc[i][3];
        float s2 = acc[i][0]*acc[i][0] + acc[i][1]*acc[i][1] + acc[i][2]*acc[i][2] + acc[i][3]*acc[i][3];
        #pragma unroll
        for (int off = 16; off >= 1; off >>= 1) {
            s  += __shfl_xor(s, off, 64);
            s2 += __shfl_xor(s2, off, 64);
        }
        float m = s * (1.f / 128.f);
        float var = s2 * (1.f / 128.f) - m * m;
        float rstd = rsqrtf(var + 1e-5f);
        int pos = pos0 + tp * 4 + i;
        #pragma unroll
        for (int j = 0; j < 4; ++j) {
            int e = te + 32 * j;
            float v = (acc[i][j] - m) * rstd * gr[j] + br[j];
            v *= x2s[pos * 128 + e];
            xfs[(tp * 4 + i) * 132 + e] = v;
        }
    }
    __syncthreads();
    #pragma unroll
    for (int i = 0; i < 4; ++i) {
        int pos = pos0 + tp * 4 + i;
        const float* xr = &xfs[(tp * 4 + i) * 132];
        float a2[4] = {0.f, 0.f, 0.f, 0.f};
        for (int ii = 0; ii < 32; ++ii) {
            #pragma unroll
            for (int j = 0; j < 4; ++j)
                a2[j] += xr[j * 32 + ii] * wt[ii * 128 + 32 * j + te];
        }
        #pragma unroll
        for (int j = 0; j < 4; ++j) out[pos * 128 + 32 * j + te] = a2[j];
    }
}

extern "C" void kernel_launch(void* const* d_in, const int* in_sizes, int n_in,
                              void* d_out, int out_size, void* d_ws, size_t ws_size,
                              hipStream_t stream) {
    (void)in_sizes; (void)n_in; (void)out_size; (void)ws_size;
    const float* x         = (const float*)d_in[0];
    const float* w1        = (const float*)d_in[1];
    const float* dw        = (const float*)d_in[2];
    const float* in_proj_w = (const float*)d_in[3];
    const float* conv1d_w  = (const float*)d_in[4];
    const float* conv1d_b  = (const float*)d_in[5];
    const float* x_proj_w  = (const float*)d_in[6];
    const float* dt_proj_w = (const float*)d_in[7];
    const float* dt_proj_b = (const float*)d_in[8];
    const float* A_log     = (const float*)d_in[9];
    const float* D_param   = (const float*)d_in[10];
    const float* out_proj_w= (const float*)d_in[11];
    const float* gamma     = (const float*)d_in[12];
    const float* beta      = (const float*)d_in[13];
    const float* w2        = (const float*)d_in[14];
    const float* wout      = (const float*)d_in[15];
    float* out = (float*)d_out;

    float* ws = (float*)d_ws;
    float* t1    = ws;                        // 4M floats; reused as u (k4 out)
    float* x2s   = ws + 4 * (size_t)MFL_;     // 4M
    float* uraw  = ws + 8 * (size_t)MFL_;     // 4M; reused as xz (k8a out)
    float* z     = ws + 12 * (size_t)MFL_;    // 4M
    float* delta = ws + 16 * (size_t)MFL_;    // 4M; first 2M shared with x1cb (k2 out, dead after k3)
    unsigned short* x1cb = (unsigned short*)(ws + 16 * (size_t)MFL_);  // NB_ ushorts
    unsigned short* ybf  = (unsigned short*)(ws + 20 * (size_t)MFL_);  // NB_ ushorts (2M floats)
    float* Bm    = ws + 22 * (size_t)MFL_;           // 262144
    float* Cm    = Bm + (size_t)NPOS_ * 8;           // 262144
    float* cA    = Cm + (size_t)NPOS_ * 8;           // 1M
    float* cB    = cA + (size_t)MFL_;                // 1M
    float* carry = cB + (size_t)MFL_;                // 1M
    unsigned short* inWb = (unsigned short*)(carry + (size_t)MFL_);    // 32768 ushorts
    unsigned short* OWb  = inWb + 32768;                               // 16384 ushorts
    float* u  = t1;
    float* xz = uraw;

    k0_cvt<<<48, 256, 0, stream>>>(in_proj_w, out_proj_w, inWb, OWb);
    k1_g1x1<<<512, 256, 0, stream>>>(x, w1, w2, t1, x2s);
    k2_dwconv<<<2048, 128, 0, stream>>>(t1, dw, x1cb);
    k3_mfma<<<512, 256, 0, stream>>>(x1cb, inWb, uraw, z);
    k4_convproj<<<2048, 128, 0, stream>>>(uraw, conv1d_w, conv1d_b, x_proj_w,
                                          dt_proj_w, dt_proj_b, u, delta, Bm, Cm);
    k5_scan1<<<1024, 128, 0, stream>>>(delta, u, Bm, A_log, cA, cB);
    k6_scan2<<<64, 128, 0, stream>>>(cA, cB, carry);
    k7_scan3<<<1024, 128, 0, stream>>>(delta, u, Bm, Cm, z, A_log, D_param, carry, ybf);
    k8a_mfma<<<256, 256, 0, stream>>>(ybf, OWb, xz);
    k8b_epi<<<1024, 256, 0, stream>>>(xz, gamma, beta, x2s, wout, out);
}

// Round 3
// 250.940 us; speedup vs baseline: 1.4546x; 1.1477x over previous
//
#include <hip/hip_runtime.h>
#include <math.h>

#define B_    8
#define C_    128
#define D_    128
#define L_    4096
#define NPOS_ 32768
#define NC_   128
#define S_    32
#define NB_   4194304      // NPOS_*128 elements
#define MFL_  1048576

typedef __attribute__((ext_vector_type(8))) short short8;
typedef __attribute__((ext_vector_type(4))) float f32x4;

__device__ __forceinline__ float siluf(float x) { return x / (1.f + __expf(-x)); }
__device__ __forceinline__ float softplusf(float x) {
    if (x > 20.f) return x;
    return log1pf(__expf(x));
}
__device__ __forceinline__ unsigned short f2bf(float f) {
    unsigned int u = __float_as_uint(f);
    u = (u + 0x7FFFu + ((u >> 16) & 1u)) >> 16;
    return (unsigned short)u;
}
__device__ __forceinline__ float bf2f(unsigned short h) {
    return __uint_as_float(((unsigned int)h) << 16);
}

// ---- K0: convert in_proj_w (32768), out_proj_w (16384), x_proj_w (3072) to bf16 ----
__global__ __launch_bounds__(256) void k0_cvt(const float* __restrict__ inW,
                                              const float* __restrict__ OW,
                                              const float* __restrict__ xpw,
                                              unsigned short* __restrict__ inWb,
                                              unsigned short* __restrict__ OWb,
                                              unsigned short* __restrict__ xpwb) {
    for (int i = blockIdx.x * 256 + threadIdx.x; i < 52224; i += gridDim.x * 256) {
        if (i < 32768)      inWb[i] = f2bf(inW[i]);
        else if (i < 49152) OWb[i - 32768] = f2bf(OW[i - 32768]);
        else                xpwb[i - 49152] = f2bf(xpw[i - 49152]);
    }
}

// ---- K1: grouped 1x1 (w1)->t1 ; silu(grouped 1x1 (w2))->x2s ----
__global__ __launch_bounds__(256) void k1_g1x1(const float* __restrict__ x,
                                               const float* __restrict__ w1,
                                               const float* __restrict__ w2,
                                               float* __restrict__ t1,
                                               float* __restrict__ x2s) {
    __shared__ float xs[16 * 128];
    int t = threadIdx.x;
    int d = t & 127, ph = t >> 7;
    int g = d >> 5, o = d & 31;
    float w1r[32], w2r[32];
    #pragma unroll
    for (int i = 0; i < 32; ++i) {
        w1r[i] = w1[g * 1024 + o * 32 + i];
        w2r[i] = w2[g * 1024 + o * 32 + i];
    }
    int pos0 = blockIdx.x * 64;
    for (int it = 0; it < 4; ++it) {
        int p0 = pos0 + it * 16;
        #pragma unroll
        for (int q = 0; q < 2; ++q) {
            int fi = t * 2 + q;
            *(float4*)&xs[fi * 4] = *(const float4*)&x[p0 * 128 + fi * 4];
        }
        __syncthreads();
        #pragma unroll
        for (int q = 0; q < 8; ++q) {
            int pl = ph * 8 + q;
            float a1 = 0.f, a2 = 0.f;
            const float* xr = &xs[pl * 128 + g * 32];
            #pragma unroll
            for (int i4 = 0; i4 < 8; ++i4) {
                float4 xv = *(const float4*)&xr[i4 * 4];
                a1 += xv.x * w1r[i4*4] + xv.y * w1r[i4*4+1] + xv.z * w1r[i4*4+2] + xv.w * w1r[i4*4+3];
                a2 += xv.x * w2r[i4*4] + xv.y * w2r[i4*4+1] + xv.z * w2r[i4*4+2] + xv.w * w2r[i4*4+3];
            }
            int pos = p0 + pl;
            t1[pos * 128 + d]  = a1;
            x2s[pos * 128 + d] = siluf(a2);
        }
        __syncthreads();
    }
}

// ---- K2: depthwise 3x3 SAME + silu -> bf16. 8x8 spatial tile, 10x10 window in VGPRs ----
__global__ __launch_bounds__(128) void k2_dwconv(const float* __restrict__ t1,
                                                 const float* __restrict__ dw,
                                                 unsigned short* __restrict__ x1cb) {
    int d = threadIdx.x;
    float dwr[9];
    #pragma unroll
    for (int k = 0; k < 9; ++k) dwr[k] = dw[k * 128 + d];
    int bid = blockIdx.x;             // 512 = b(8) * ht(8) * wt(8)
    int wt = bid & 7, ht = (bid >> 3) & 7, b = bid >> 6;
    int h0 = ht * 8, w0 = wt * 8;
    float rows[10][10];
    #pragma unroll
    for (int r = 0; r < 10; ++r) {
        int hh = h0 - 1 + r;
        bool hv = (hh >= 0) && (hh < 64);
        #pragma unroll
        for (int c = 0; c < 10; ++c) {
            int w = w0 - 1 + c;
            bool wvv = (w >= 0) && (w < 64);
            rows[r][c] = (hv && wvv) ? t1[((b * 64 + hh) * 64 + w) * 128 + d] : 0.f;
        }
    }
    #pragma unroll
    for (int hi = 0; hi < 8; ++hi) {
        #pragma unroll
        for (int wi = 0; wi < 8; ++wi) {
            float acc = rows[hi][wi]     * dwr[0] + rows[hi][wi+1]   * dwr[1] + rows[hi][wi+2]   * dwr[2]
                      + rows[hi+1][wi]   * dwr[3] + rows[hi+1][wi+1] * dwr[4] + rows[hi+1][wi+2] * dwr[5]
                      + rows[hi+2][wi]   * dwr[6] + rows[hi+2][wi+1] * dwr[7] + rows[hi+2][wi+2] * dwr[8];
            x1cb[((b * 64 + h0 + hi) * 64 + w0 + wi) * 128 + d] = f2bf(siluf(acc));
        }
    }
}

// ---- K3: in_proj via bf16 MFMA -> uraw fp32, z bf16 ----
__global__ __launch_bounds__(256) void k3_mfma(const unsigned short* __restrict__ Abf,
                                               const unsigned short* __restrict__ Bbf,
                                               float* __restrict__ uraw,
                                               unsigned short* __restrict__ zb) {
    __shared__ unsigned short Al[128 * 72];
    __shared__ unsigned short Bl[128 * 72];
    int t = threadIdx.x;
    int mtile = blockIdx.x >> 1, ntile = blockIdx.x & 1;
    int pos0 = mtile * 128, n0g = ntile * 128;
    int lane = t & 63, wv = t >> 6;
    int m0 = (wv & 1) * 64, n0w = (wv >> 1) * 64;
    int lanem = lane & 15, laneq = lane >> 4;
    f32x4 acc[4][4];
    #pragma unroll
    for (int i = 0; i < 4; ++i)
        #pragma unroll
        for (int j = 0; j < 4; ++j) acc[i][j] = (f32x4){0.f, 0.f, 0.f, 0.f};
    for (int kc = 0; kc < 2; ++kc) {
        #pragma unroll
        for (int q = 0; q < 4; ++q) {
            int c = t + q * 256;
            int row = c >> 3, col = c & 7;
            *(int4*)&Al[row * 72 + col * 8] = *(const int4*)&Abf[(pos0 + row) * 128 + kc * 64 + col * 8];
            *(int4*)&Bl[row * 72 + col * 8] = *(const int4*)&Bbf[(n0g + row) * 128 + kc * 64 + col * 8];
        }
        __syncthreads();
        #pragma unroll
        for (int ks = 0; ks < 2; ++ks) {
            short8 af[4], bfr[4];
            #pragma unroll
            for (int mi = 0; mi < 4; ++mi)
                af[mi] = *(const short8*)&Al[(m0 + mi * 16 + lanem) * 72 + ks * 32 + laneq * 8];
            #pragma unroll
            for (int ni = 0; ni < 4; ++ni)
                bfr[ni] = *(const short8*)&Bl[(n0w + ni * 16 + lanem) * 72 + ks * 32 + laneq * 8];
            #pragma unroll
            for (int mi = 0; mi < 4; ++mi)
                #pragma unroll
                for (int ni = 0; ni < 4; ++ni)
                    acc[mi][ni] = __builtin_amdgcn_mfma_f32_16x16x32_bf16(af[mi], bfr[ni], acc[mi][ni], 0, 0, 0);
        }
        __syncthreads();
    }
    #pragma unroll
    for (int mi = 0; mi < 4; ++mi)
        #pragma unroll
        for (int ni = 0; ni < 4; ++ni)
            #pragma unroll
            for (int r = 0; r < 4; ++r) {
                int m = pos0 + m0 + mi * 16 + laneq * 4 + r;
                int n = n0w + ni * 16 + lanem;
                if (ntile) zb[m * 128 + n] = f2bf(acc[mi][ni][r]);
                else       uraw[m * 128 + n] = acc[mi][ni][r];
            }
}

// ---- K4: conv1d+silu -> u fp32 + bf16 LDS ; x_proj via MFMA ; delta/Bm/Cm epilogue ----
// 256 thr, 64 positions/block, grid 512.
__global__ __launch_bounds__(256) void k4_convproj(const float* __restrict__ uraw,
                                                   const float* __restrict__ cw,
                                                   const float* __restrict__ cb,
                                                   const unsigned short* __restrict__ xpwb,
                                                   const float* __restrict__ dtw,
                                                   const float* __restrict__ dtb,
                                                   float* __restrict__ u,
                                                   float* __restrict__ delta,
                                                   float* __restrict__ Bm,
                                                   float* __restrict__ Cm) {
    __shared__ unsigned short uA[64 * 136];
    __shared__ unsigned short xB[32 * 136];
    __shared__ float xdb[64 * 36];
    int t = threadIdx.x;
    int d = t & 127, ph = t >> 7;
    // stage xpw (24x128 bf16, pad rows to 32 with zero)
    for (int i = t; i < 32 * 128; i += 256) {
        int n = i >> 7, k = i & 127;
        xB[n * 136 + k] = (n < 24) ? xpwb[n * 128 + k] : (unsigned short)0;
    }
    float cw0 = cw[d * 3 + 0], cw1 = cw[d * 3 + 1], cw2 = cw[d * 3 + 2], cbr = cb[d];
    float dtwr[8];
    #pragma unroll
    for (int r = 0; r < 8; ++r) dtwr[r] = dtw[d * 8 + r];
    float dtbr = dtb[d];

    int gpos0 = blockIdx.x * 64;
    int ll0 = (gpos0 & 4095) + ph * 32;
    int base = (gpos0 + ph * 32) * 128 + d;
    float ur0 = (ll0 >= 2) ? uraw[base - 256] : 0.f;
    float ur1 = (ll0 >= 1) ? uraw[base - 128] : 0.f;
    #pragma unroll
    for (int q = 0; q < 32; ++q) {
        float urq = uraw[base + q * 128];
        float us = siluf(ur0 * cw0 + ur1 * cw1 + urq * cw2 + cbr);
        u[base + q * 128] = us;
        uA[(ph * 32 + q) * 136 + d] = f2bf(us);
        ur0 = ur1; ur1 = urq;
    }
    __syncthreads();
    // MFMA: wave wv handles m-tile wv*16; output 64 pos x 32 e
    int lane = t & 63, wv = t >> 6;
    int lanem = lane & 15, laneq = lane >> 4;
    f32x4 accx[2];
    accx[0] = (f32x4){0.f, 0.f, 0.f, 0.f};
    accx[1] = (f32x4){0.f, 0.f, 0.f, 0.f};
    #pragma unroll
    for (int ks = 0; ks < 4; ++ks) {
        short8 af = *(const short8*)&uA[(wv * 16 + lanem) * 136 + ks * 32 + laneq * 8];
        #pragma unroll
        for (int nj = 0; nj < 2; ++nj) {
            short8 bfr = *(const short8*)&xB[(nj * 16 + lanem) * 136 + ks * 32 + laneq * 8];
            accx[nj] = __builtin_amdgcn_mfma_f32_16x16x32_bf16(af, bfr, accx[nj], 0, 0, 0);
        }
    }
    #pragma unroll
    for (int nj = 0; nj < 2; ++nj)
        #pragma unroll
        for (int r = 0; r < 4; ++r)
            xdb[(wv * 16 + laneq * 4 + r) * 36 + nj * 16 + lanem] = accx[nj][r];
    __syncthreads();
    // delta = softplus(dtb + x_dbl[:, :8] @ dtw^T)
    #pragma unroll
    for (int q = 0; q < 32; ++q) {
        int pl = ph * 32 + q;
        float dt = dtbr;
        #pragma unroll
        for (int r = 0; r < 8; ++r) dt += xdb[pl * 36 + r] * dtwr[r];
        delta[base + q * 128] = softplusf(dt);
    }
    // Bm/Cm
    for (int i = t; i < 1024; i += 256) {
        int p = i >> 4, j = i & 15;
        float v = xdb[p * 36 + 8 + j];
        int gp = gpos0 + p;
        if (j < 8) Bm[gp * 8 + j] = v;
        else       Cm[gp * 8 + (j - 8)] = v;
    }
}

// ---- K5: scan phase 1 ----
__global__ __launch_bounds__(128) void k5_scan1(const float* __restrict__ delta,
                                                const float* __restrict__ u,
                                                const float* __restrict__ Bm,
                                                const float* __restrict__ A_log,
                                                float* __restrict__ cA,
                                                float* __restrict__ cB) {
    int d = threadIdx.x;
    int bc = blockIdx.x;
    int b = bc >> 7, c = bc & 127;
    float Ar[8];
    #pragma unroll
    for (int n = 0; n < 8; ++n) Ar[n] = -__expf(A_log[d * 8 + n]);
    float h[8], ap[8];
    #pragma unroll
    for (int n = 0; n < 8; ++n) { h[n] = 0.f; ap[n] = 1.f; }
    int base  = (b * L_ + c * S_) * 128 + d;
    int bbase = (b * L_ + c * S_) * 8;
    for (int s = 0; s < S_; ++s) {
        float dl = delta[base + s * 128];
        float uv = u[base + s * 128];
        float du = dl * uv;
        float4 bm0 = *(const float4*)&Bm[bbase + s * 8];
        float4 bm1 = *(const float4*)&Bm[bbase + s * 8 + 4];
        float a;
        a = __expf(dl * Ar[0]); ap[0] *= a; h[0] = a * h[0] + du * bm0.x;
        a = __expf(dl * Ar[1]); ap[1] *= a; h[1] = a * h[1] + du * bm0.y;
        a = __expf(dl * Ar[2]); ap[2] *= a; h[2] = a * h[2] + du * bm0.z;
        a = __expf(dl * Ar[3]); ap[3] *= a; h[3] = a * h[3] + du * bm0.w;
        a = __expf(dl * Ar[4]); ap[4] *= a; h[4] = a * h[4] + du * bm1.x;
        a = __expf(dl * Ar[5]); ap[5] *= a; h[5] = a * h[5] + du * bm1.y;
        a = __expf(dl * Ar[6]); ap[6] *= a; h[6] = a * h[6] + du * bm1.z;
        a = __expf(dl * Ar[7]); ap[7] *= a; h[7] = a * h[7] + du * bm1.w;
    }
    int obase = (bc * 128 + d) * 8;
    *(float4*)&cA[obase]     = make_float4(ap[0], ap[1], ap[2], ap[3]);
    *(float4*)&cA[obase + 4] = make_float4(ap[4], ap[5], ap[6], ap[7]);
    *(float4*)&cB[obase]     = make_float4(h[0], h[1], h[2], h[3]);
    *(float4*)&cB[obase + 4] = make_float4(h[4], h[5], h[6], h[7]);
}

// ---- K6: scan phase 2 ----
__global__ __launch_bounds__(128) void k6_scan2(const float* __restrict__ cA,
                                                const float* __restrict__ cB,
                                                float* __restrict__ carry) {
    int b = blockIdx.x >> 3;
    int slice = blockIdx.x & 7;
    int dn = slice * 128 + threadIdx.x;
    float h = 0.f;
    for (int c = 0; c < NC_; ++c) {
        int idx = (b * NC_ + c) * 1024 + dn;
        float a  = cA[idx];
        float bv = cB[idx];
        carry[idx] = h;
        h = a * h + bv;
    }
}

// ---- K7: scan phase 3, emit y (bf16) ----
__global__ __launch_bounds__(128) void k7_scan3(const float* __restrict__ delta,
                                                const float* __restrict__ u,
                                                const float* __restrict__ Bm,
                                                const float* __restrict__ Cm,
                                                const unsigned short* __restrict__ zb,
                                                const float* __restrict__ A_log,
                                                const float* __restrict__ Dp,
                                                const float* __restrict__ carry,
                                                unsigned short* __restrict__ ybf) {
    int d = threadIdx.x;
    int bc = blockIdx.x;
    int b = bc >> 7, c = bc & 127;
    float Ar[8];
    #pragma unroll
    for (int n = 0; n < 8; ++n) Ar[n] = -__expf(A_log[d * 8 + n]);
    float Dpr = Dp[d];
    int cbase = (bc * 128 + d) * 8;
    float4 h0 = *(const float4*)&carry[cbase];
    float4 h1 = *(const float4*)&carry[cbase + 4];
    float h[8] = {h0.x, h0.y, h0.z, h0.w, h1.x, h1.y, h1.z, h1.w};
    int base  = (b * L_ + c * S_) * 128 + d;
    int bbase = (b * L_ + c * S_) * 8;
    for (int s = 0; s < S_; ++s) {
        float dl = delta[base + s * 128];
        float uv = u[base + s * 128];
        float zv = bf2f(zb[base + s * 128]);
        float du = dl * uv;
        float4 bm0 = *(const float4*)&Bm[bbase + s * 8];
        float4 bm1 = *(const float4*)&Bm[bbase + s * 8 + 4];
        float4 cm0 = *(const float4*)&Cm[bbase + s * 8];
        float4 cm1 = *(const float4*)&Cm[bbase + s * 8 + 4];
        float a;
        a = __expf(dl * Ar[0]); h[0] = a * h[0] + du * bm0.x;
        a = __expf(dl * Ar[1]); h[1] = a * h[1] + du * bm0.y;
        a = __expf(dl * Ar[2]); h[2] = a * h[2] + du * bm0.z;
        a = __expf(dl * Ar[3]); h[3] = a * h[3] + du * bm0.w;
        a = __expf(dl * Ar[4]); h[4] = a * h[4] + du * bm1.x;
        a = __expf(dl * Ar[5]); h[5] = a * h[5] + du * bm1.y;
        a = __expf(dl * Ar[6]); h[6] = a * h[6] + du * bm1.z;
        a = __expf(dl * Ar[7]); h[7] = a * h[7] + du * bm1.w;
        float yv = h[0] * cm0.x + h[1] * cm0.y + h[2] * cm0.z + h[3] * cm0.w
                 + h[4] * cm1.x + h[5] * cm1.y + h[6] * cm1.z + h[7] * cm1.w;
        yv = (yv + uv * Dpr) * siluf(zv);
        ybf[base + s * 128] = f2bf(yv);
    }
}

// ---- K8a: out_proj via bf16 MFMA -> xz fp32 ----
__global__ __launch_bounds__(256) void k8a_mfma(const unsigned short* __restrict__ Abf,
                                                const unsigned short* __restrict__ Bbf,
                                                float* __restrict__ xz) {
    __shared__ unsigned short Al[128 * 72];
    __shared__ unsigned short Bl[128 * 72];
    int t = threadIdx.x;
    int pos0 = blockIdx.x * 128;
    int lane = t & 63, wv = t >> 6;
    int m0 = (wv & 1) * 64, n0w = (wv >> 1) * 64;
    int lanem = lane & 15, laneq = lane >> 4;
    f32x4 acc[4][4];
    #pragma unroll
    for (int i = 0; i < 4; ++i)
        #pragma unroll
        for (int j = 0; j < 4; ++j) acc[i][j] = (f32x4){0.f, 0.f, 0.f, 0.f};
    for (int kc = 0; kc < 2; ++kc) {
        #pragma unroll
        for (int q = 0; q < 4; ++q) {
            int c = t + q * 256;
            int row = c >> 3, col = c & 7;
            *(int4*)&Al[row * 72 + col * 8] = *(const int4*)&Abf[(pos0 + row) * 128 + kc * 64 + col * 8];
            *(int4*)&Bl[row * 72 + col * 8] = *(const int4*)&Bbf[row * 128 + kc * 64 + col * 8];
        }
        __syncthreads();
        #pragma unroll
        for (int ks = 0; ks < 2; ++ks) {
            short8 af[4], bfr[4];
            #pragma unroll
            for (int mi = 0; mi < 4; ++mi)
                af[mi] = *(const short8*)&Al[(m0 + mi * 16 + lanem) * 72 + ks * 32 + laneq * 8];
            #pragma unroll
            for (int ni = 0; ni < 4; ++ni)
                bfr[ni] = *(const short8*)&Bl[(n0w + ni * 16 + lanem) * 72 + ks * 32 + laneq * 8];
            #pragma unroll
            for (int mi = 0; mi < 4; ++mi)
                #pragma unroll
                for (int ni = 0; ni < 4; ++ni)
                    acc[mi][ni] = __builtin_amdgcn_mfma_f32_16x16x32_bf16(af[mi], bfr[ni], acc[mi][ni], 0, 0, 0);
        }
        __syncthreads();
    }
    #pragma unroll
    for (int mi = 0; mi < 4; ++mi)
        #pragma unroll
        for (int ni = 0; ni < 4; ++ni)
            #pragma unroll
            for (int r = 0; r < 4; ++r) {
                int m = pos0 + m0 + mi * 16 + laneq * 4 + r;
                int n = n0w + ni * 16 + lanem;
                xz[m * 128 + n] = acc[mi][ni][r];
            }
}

// ---- K8b: LayerNorm + *x2s + grouped 1x1 (wout, fp32) -> out ----
__global__ __launch_bounds__(256) void k8b_epi(const float* __restrict__ xz,
                                               const float* __restrict__ gamma,
                                               const float* __restrict__ beta,
                                               const float* __restrict__ x2s,
                                               const float* __restrict__ wout,
                                               float* __restrict__ out) {
    __shared__ float wt[32 * 128];
    __shared__ float xfs[32 * 132];
    int t  = threadIdx.x;
    int te = t & 31, tp = t >> 5;
    for (int idx = t; idx < 4096; idx += 256) {
        int i = idx >> 7, c = idx & 127;
        wt[idx] = wout[(c >> 5) * 1024 + (c & 31) * 32 + i];
    }
    float gr[4], br[4];
    #pragma unroll
    for (int j = 0; j < 4; ++j) { gr[j] = gamma[te + 32 * j]; br[j] = beta[te + 32 * j]; }

    int pos0 = blockIdx.x * 32;
    float acc[4][4];
    #pragma unroll
    for (int i = 0; i < 4; ++i) {
        int pos = pos0 + tp * 4 + i;
        #pragma unroll
        for (int j = 0; j < 4; ++j) acc[i][j] = xz[pos * 128 + te + 32 * j];
    }
    #pragma unroll
    for (int i = 0; i < 4; ++i) {
        float s  = acc[i][0] + acc[i][1] + acc[i][2] + acc[i][3];
        float s2 = acc[i][0]*acc[i][0] + acc[i][1]*acc[i][1] + acc[i][2]*acc[i][2] + acc[i][3]*acc[i][3];
        #pragma unroll
        for (int off = 16; off >= 1; off >>= 1) {
            s  += __shfl_xor(s, off, 64);
            s2 += __shfl_xor(s2, off, 64);
        }
        float m = s * (1.f / 128.f);
        float var = s2 * (1.f / 128.f) - m * m;
        float rstd = rsqrtf(var + 1e-5f);
        int pos = pos0 + tp * 4 + i;
        #pragma unroll
        for (int j = 0; j < 4; ++j) {
            int e = te + 32 * j;
            float v = (acc[i][j] - m) * rstd * gr[j] + br[j];
            v *= x2s[pos * 128 + e];
            xfs[(tp * 4 + i) * 132 + e] = v;
        }
    }
    __syncthreads();
    #pragma unroll
    for (int i = 0; i < 4; ++i) {
        int pos = pos0 + tp * 4 + i;
        const float* xr = &xfs[(tp * 4 + i) * 132];
        float a2[4] = {0.f, 0.f, 0.f, 0.f};
        for (int ii = 0; ii < 32; ++ii) {
            #pragma unroll
            for (int j = 0; j < 4; ++j)
                a2[j] += xr[j * 32 + ii] * wt[ii * 128 + 32 * j + te];
        }
        #pragma unroll
        for (int j = 0; j < 4; ++j) out[pos * 128 + 32 * j + te] = a2[j];
    }
}

extern "C" void kernel_launch(void* const* d_in, const int* in_sizes, int n_in,
                              void* d_out, int out_size, void* d_ws, size_t ws_size,
                              hipStream_t stream) {
    (void)in_sizes; (void)n_in; (void)out_size; (void)ws_size;
    const float* x         = (const float*)d_in[0];
    const float* w1        = (const float*)d_in[1];
    const float* dw        = (const float*)d_in[2];
    const float* in_proj_w = (const float*)d_in[3];
    const float* conv1d_w  = (const float*)d_in[4];
    const float* conv1d_b  = (const float*)d_in[5];
    const float* x_proj_w  = (const float*)d_in[6];
    const float* dt_proj_w = (const float*)d_in[7];
    const float* dt_proj_b = (const float*)d_in[8];
    const float* A_log     = (const float*)d_in[9];
    const float* D_param   = (const float*)d_in[10];
    const float* out_proj_w= (const float*)d_in[11];
    const float* gamma     = (const float*)d_in[12];
    const float* beta      = (const float*)d_in[13];
    const float* w2        = (const float*)d_in[14];
    const float* wout      = (const float*)d_in[15];
    float* out = (float*)d_out;

    float* ws = (float*)d_ws;
    float* t1    = ws;                        // 4M floats; reused as u (k4 out)
    float* x2s   = ws + 4 * (size_t)MFL_;     // 4M
    float* uraw  = ws + 8 * (size_t)MFL_;     // 4M; reused as xz (k8a out)
    unsigned short* zb = (unsigned short*)(ws + 12 * (size_t)MFL_);    // NB_ ushorts (2M floats)
    float* delta = ws + 16 * (size_t)MFL_;    // 4M; first 2M aliased by x1cb (dead after k3)
    unsigned short* x1cb = (unsigned short*)(ws + 16 * (size_t)MFL_);
    unsigned short* ybf  = (unsigned short*)(ws + 20 * (size_t)MFL_);  // NB_ ushorts
    float* Bm    = ws + 22 * (size_t)MFL_;           // 262144
    float* Cm    = Bm + (size_t)NPOS_ * 8;           // 262144
    float* cA    = Cm + (size_t)NPOS_ * 8;           // 1M
    float* cB    = cA + (size_t)MFL_;                // 1M
    float* carry = cB + (size_t)MFL_;                // 1M
    unsigned short* inWb = (unsigned short*)(carry + (size_t)MFL_);    // 32768
    unsigned short* OWb  = inWb + 32768;                               // 16384
    unsigned short* xpwb = OWb + 16384;                                // 3072
    float* u  = t1;
    float* xz = uraw;

    k0_cvt<<<64, 256, 0, stream>>>(in_proj_w, out_proj_w, x_proj_w, inWb, OWb, xpwb);
    k1_g1x1<<<512, 256, 0, stream>>>(x, w1, w2, t1, x2s);
    k2_dwconv<<<512, 128, 0, stream>>>(t1, dw, x1cb);
    k3_mfma<<<512, 256, 0, stream>>>(x1cb, inWb, uraw, zb);
    k4_convproj<<<512, 256, 0, stream>>>(uraw, conv1d_w, conv1d_b, xpwb,
                                         dt_proj_w, dt_proj_b, u, delta, Bm, Cm);
    k5_scan1<<<1024, 128, 0, stream>>>(delta, u, Bm, A_log, cA, cB);
    k6_scan2<<<64, 128, 0, stream>>>(cA, cB, carry);
    k7_scan3<<<1024, 128, 0, stream>>>(delta, u, Bm, Cm, zb, A_log, D_param, carry, ybf);
    k8a_mfma<<<256, 256, 0, stream>>>(ybf, OWb, xz);
    k8b_epi<<<1024, 256, 0, stream>>>(xz, gamma, beta, x2s, wout, out);
}